// Round 2
// baseline (2519.051 us; speedup 1.0000x reference)
//
#include <hip/hip_runtime.h>
#include <math.h>

#define NMAT 50000
#define MPB 8                    // matrices per block: 256 thr = 4 waves = 8 half-waves
#define NBLK (NMAT / MPB)        // 6250

__device__ __forceinline__ float frcp(float x)  { return __builtin_amdgcn_rcpf(x); }
__device__ __forceinline__ float frsq(float x)  { return __builtin_amdgcn_rsqf(x); }
__device__ __forceinline__ float fsqrt_(float x){ return __builtin_amdgcn_sqrtf(x); }

// sum across the 32-lane half-wave (all lanes get the result)
__device__ __forceinline__ float red32(float x) {
  x += __shfl_xor(x, 1, 32);
  x += __shfl_xor(x, 2, 32);
  x += __shfl_xor(x, 4, 32);
  x += __shfl_xor(x, 8, 32);
  x += __shfl_xor(x, 16, 32);
  return x;
}

// block=256, 4 waves/EU: caps VGPR at 128 -> 16 waves/CU (LDS also allows 4 blocks/CU)
__global__ __launch_bounds__(256, 4) void riem_batch(const float* __restrict__ X,
                                                     const float* __restrict__ Y,
                                                     float* __restrict__ partial) {
  const int tid = threadIdx.x;
  const int c   = tid & 31;        // column owned by this lane
  const int hw  = tid >> 5;        // half-wave id within block (0..7)
  const long mat = (long)blockIdx.x * MPB + hw;
  const float* Yp = Y + mat * 1024;
  const float* Xp = X + mat * 1024;

  __shared__ float tbuf[MPB][1056];   // 32x33 padded transpose buffer, half-wave private
  __shared__ float psum[MPB];

  // ---- load Y columns: lane c holds Y[:,c] ----
  float m[32];
#pragma unroll
  for (int i = 0; i < 32; ++i) m[i] = Yp[i * 32 + c];

  // ---- square-root-free symmetric elimination: Y = Lt * D * Lt^T ----
  float dc = 1.0f, rc = 1.0f;
#pragma unroll
  for (int j = 0; j < 32; ++j) {
    float piv  = __shfl(m[j], j, 32);      // D[j], uniform per half-wave
    float rinv = frcp(piv);
    if (c == j) { dc = piv; rc = rinv; }
    float t = (c > j) ? m[j] * rinv : 0.0f;   // frozen columns (c<=j) untouched
#pragma unroll
    for (int i = j + 1; i < 32; ++i)
      m[i] = fmaf(-__shfl(m[i], j, 32), t, m[i]);
  }
  float dsv = frsq(dc);                     // D[c]^{-1/2}
#pragma unroll
  for (int i = 0; i < 32; ++i) m[i] *= rc;  // unit-lower Lt columns

  // ---- load X columns, forward solve W = Lt^{-1} X ----
  float x[32];
#pragma unroll
  for (int i = 0; i < 32; ++i) x[i] = Xp[i * 32 + c];
#pragma unroll
  for (int k = 0; k < 31; ++k) {
#pragma unroll
    for (int i = k + 1; i < 32; ++i)
      x[i] = fmaf(-__shfl(m[i], k, 32), x[k], x[i]);
  }

  // ---- transpose W within the half-wave via padded LDS (half-wave private:
  //      same wave writes then reads, LDS ops are wave-ordered -> no barrier) ----
  float* tb = tbuf[hw];
#pragma unroll
  for (int i = 0; i < 32; ++i) tb[c * 33 + i] = x[i];
#pragma unroll
  for (int i = 0; i < 32; ++i) x[i] = tb[i * 33 + c];

  // ---- second solve: V = Lt^{-1} W^T, then A = D^{-1/2} V D^{-1/2} ----
#pragma unroll
  for (int k = 0; k < 31; ++k) {
#pragma unroll
    for (int i = k + 1; i < 32; ++i)
      x[i] = fmaf(-__shfl(m[i], k, 32), x[k], x[i]);
  }
#pragma unroll
  for (int i = 0; i < 32; ++i) x[i] = x[i] * __shfl(dsv, i, 32) * dsv;
  // m[] is dead from here on

  // ---- Householder tridiagonalization; extract d[k]/e2[k] in-loop so their
  //      registers are born exactly as x[k] dies (peak live stays ~x[32]) ----
  float d[32], e2[31];
  float e2max = 0.0f, dminv = 1e30f, dmaxv = -1e30f;
#pragma unroll
  for (int k = 0; k < 30; ++k) {
    float colv  = x[k];                              // A[c][k]
    float dkk   = __shfl(x[k], k, 32);               // A[k][k], final at step k
    d[k] = dkk; dminv = fminf(dminv, dkk); dmaxv = fmaxf(dmaxv, dkk);
    float sq    = (c > k) ? colv * colv : 0.0f;
    float sigma = red32(sq);                         // ||A[k+1:,k]||^2
    float akk1  = __shfl(x[k], k + 1, 32);           // A[k+1][k]
    e2[k] = sigma;                                   // e_k^2 = sigma exactly
    e2max = fmaxf(e2max, sigma);
    float nrm   = fsqrt_(sigma);
    float alpha = (akk1 >= 0.0f) ? -nrm : nrm;
    float denom = fmaf(-alpha, akk1, sigma);         // vTv/2
    float tau   = frcp(fmaxf(denom, 1e-35f));        // sigma==0 -> v==0 no-op
    float v     = (c == k + 1) ? (akk1 - alpha) : ((c > k + 1) ? colv : 0.0f);
    float acc = 0.0f;
#pragma unroll
    for (int j = k + 1; j < 32; ++j) acc = fmaf(x[j], __shfl(v, j, 32), acc);
    float p = tau * acc;                             // p = tau * A v
    float K = 0.5f * tau * red32(v * p);             // (tau/2) vTp
    float q = fmaf(-K, v, p);
#pragma unroll
    for (int j = k + 1; j < 32; ++j) {               // A -= v q^T + q v^T
      float vb = __shfl(v, j, 32);
      float qb = __shfl(q, j, 32);
      x[j] = fmaf(-v, qb, fmaf(-q, vb, x[j]));
    }
  }
  {
    float d30 = __shfl(x[30], 30, 32);
    float d31 = __shfl(x[31], 31, 32);
    float el  = __shfl(x[30], 31, 32);               // trailing subdiagonal
    d[30] = d30; d[31] = d31;
    e2[30] = el * el;
    e2max  = fmaxf(e2max, e2[30]);
    dminv = fminf(dminv, fminf(d30, d31));
    dmaxv = fmaxf(dmaxv, fmaxf(d30, d31));
  }
  // x[] is dead from here on

  // ---- Gershgorin bounds ----
  float er = 2.0f * fsqrt_(e2max);
  float lo = fmaxf(dminv - er, 1e-3f);   // A is SPD, lambda_min >~ 0.15 by construction
  float hi = dmaxv + er;

  // ---- bisection with Sturm counts: lane c converges to eigenvalue #c ----
  for (int it = 0; it < 18; ++it) {
    float mid = 0.5f * (lo + hi);
    float qq  = d[0] - mid;
    qq = (fabsf(qq) < 1e-30f) ? -1e-30f : qq;
    int cnt = (qq < 0.0f) ? 1 : 0;
#pragma unroll
    for (int i = 1; i < 32; ++i) {
      qq = (d[i] - mid) - e2[i - 1] * frcp(qq);
      qq = (fabsf(qq) < 1e-30f) ? -1e-30f : qq;      // pivmin clamp: no inf*0
      cnt += (qq < 0.0f) ? 1 : 0;
    }
    bool le = (cnt <= c);
    lo = le ? mid : lo;
    hi = le ? hi : mid;
  }

  float lam = 0.5f * (lo + hi);
  float lg  = __logf(lam);
  float s   = red32(lg * lg);
  float db  = fsqrt_(s);                 // d(x_b, y_b)

  if (c == 0) psum[hw] = db;
  __syncthreads();
  if (tid == 0) {
    float t = 0.0f;
#pragma unroll
    for (int i = 0; i < MPB; ++i) t += psum[i];
    partial[blockIdx.x] = t;
  }
}

__global__ __launch_bounds__(256) void riem_finish(const float* __restrict__ partial,
                                                   float* __restrict__ out) {
  float acc = 0.0f;
  for (int i = threadIdx.x; i < NBLK; i += 256) acc += partial[i];
  acc += __shfl_xor(acc, 1);
  acc += __shfl_xor(acc, 2);
  acc += __shfl_xor(acc, 4);
  acc += __shfl_xor(acc, 8);
  acc += __shfl_xor(acc, 16);
  acc += __shfl_xor(acc, 32);
  __shared__ float ps[4];
  if ((threadIdx.x & 63) == 0) ps[threadIdx.x >> 6] = acc;
  __syncthreads();
  if (threadIdx.x == 0)
    out[0] = (ps[0] + ps[1] + ps[2] + ps[3]) * (1.0f / (float)NMAT);
}

extern "C" void kernel_launch(void* const* d_in, const int* in_sizes, int n_in,
                              void* d_out, int out_size, void* d_ws, size_t ws_size,
                              hipStream_t stream) {
  const float* x = (const float*)d_in[0];
  const float* y = (const float*)d_in[1];
  float* out  = (float*)d_out;
  float* part = (float*)d_ws;   // NBLK floats = 25 KB
  riem_batch<<<NBLK, 256, 0, stream>>>(x, y, part);
  riem_finish<<<1, 256, 0, stream>>>(part, out);
}

// Round 3
// 1712.281 us; speedup vs baseline: 1.4712x; 1.4712x over previous
//
#include <hip/hip_runtime.h>
#include <math.h>

#define NMAT 50000
#define MPB 8                    // matrices per block: 256 thr = 4 waves = 8 half-waves
#define NBLK (NMAT / MPB)        // 6250

__device__ __forceinline__ float frcp(float x)  { return __builtin_amdgcn_rcpf(x); }
__device__ __forceinline__ float frsq(float x)  { return __builtin_amdgcn_rsqf(x); }
__device__ __forceinline__ float fsqrt_(float x){ return __builtin_amdgcn_sqrtf(x); }

// x + rotate-right-by-n within rows of 16 (VALU pipe, not LDS pipe)
#define DPP_ROR_ADD(x, ctrl) \
  ((x) + __int_as_float(__builtin_amdgcn_update_dpp(0, __float_as_int(x), (ctrl), 0xF, 0xF, false)))

// sum across the 32-lane half-wave, all lanes get the result.
// 4 DPP rotate-adds give every lane its row-of-16 sum; one xor16 swizzle merges.
__device__ __forceinline__ float red32(float x) {
  x = DPP_ROR_ADD(x, 0x121);   // row_ror:1
  x = DPP_ROR_ADD(x, 0x122);   // row_ror:2
  x = DPP_ROR_ADD(x, 0x124);   // row_ror:4
  x = DPP_ROR_ADD(x, 0x128);   // row_ror:8
  x += __shfl_xor(x, 16, 32);
  return x;
}

__device__ __forceinline__ float f4c(const float4& v, int e) {
  return e == 0 ? v.x : e == 1 ? v.y : e == 2 ? v.z : v.w;   // e is compile-time
}

// (256,2): by round-2's observed mapping (arg 4 -> 64 VGPR cap), arg 2 -> 128.
__global__ __launch_bounds__(256, 2) void riem_batch(const float* __restrict__ X,
                                                     const float* __restrict__ Y,
                                                     float* __restrict__ partial) {
  const int tid = threadIdx.x;
  const int c   = tid & 31;        // column owned by this lane
  const int hw  = tid >> 5;        // half-wave id within block (0..7)
  const long mat = (long)blockIdx.x * MPB + hw;
  const float* Yp = Y + mat * 1024;
  const float* Xp = X + mat * 1024;

  // Lb[h][j*32+i] = L[i][j] (column j contiguous -> conflict-free writes,
  // uniform-address float4 broadcast reads). No padding needed.
  __shared__ __align__(16) float Lb[MPB][1024];
  __shared__ __align__(16) float vb[MPB][32];
  __shared__ __align__(16) float qb[MPB][32];
  __shared__ float psum[MPB];

  float* Lh = Lb[hw];
  float* vh = vb[hw];
  float* qh = qb[hw];

  // ---- load Y columns: lane c holds Y[:,c] ----
  float m[32];
#pragma unroll
  for (int i = 0; i < 32; ++i) m[i] = Yp[i * 32 + c];

  // ---- square-root-free symmetric elimination Y = L D L^T, L -> LDS ----
  // update: M[i][c] -= L[i][j] * M[j][c]  (L[i][j] uniform from LDS, M[j][c]=m[j] per lane)
  float dc = 1.0f;
#pragma unroll
  for (int j = 0; j < 32; ++j) {
    float piv  = __shfl(m[j], j, 32);          // D[j], uniform per half-wave
    float rinv = frcp(piv);
    if (c == j) dc = piv;
    Lh[j * 32 + c] = m[j] * rinv;              // L[c][j]; diag=1; junk for c<j (never read)
    float mj = m[j];
#pragma unroll
    for (int g = 0; g < 8; ++g) {
      if (4 * g + 3 <= j) continue;            // group has no i > j
      float4 L4 = *(const float4*)(Lh + j * 32 + 4 * g);   // uniform broadcast read
#pragma unroll
      for (int e = 0; e < 4; ++e) {
        int i = 4 * g + e;
        if (i > j) m[i] = fmaf(-f4c(L4, e), mj, m[i]);
      }
    }
  }
  float dsv = frsq(dc);                        // D[c]^{-1/2}
  // m[] dead from here

  // ---- load X, forward solve W = L^{-1} X ----
  float x[32];
#pragma unroll
  for (int i = 0; i < 32; ++i) x[i] = Xp[i * 32 + c];
#pragma unroll
  for (int k = 0; k < 31; ++k) {
    float xk = x[k];
#pragma unroll
    for (int g = 0; g < 8; ++g) {
      if (4 * g + 3 <= k) continue;
      float4 L4 = *(const float4*)(Lh + k * 32 + 4 * g);
#pragma unroll
      for (int e = 0; e < 4; ++e) {
        int i = 4 * g + e;
        if (i > k) x[i] = fmaf(-f4c(L4, e), xk, x[i]);
      }
    }
  }

  // ---- in-register 32x32 butterfly transpose (block-swap recursion) ----
#pragma unroll
  for (int s = 16; s >= 1; s >>= 1) {
    const bool up = (c & s) != 0;
#pragma unroll
    for (int i = 0; i < 32; ++i) {
      if (i & s) continue;                     // compile-time skip
      const int h2 = i | s;
      float send = up ? x[i] : x[h2];
      float rec  = __shfl_xor(send, s, 32);
      x[i]  = up ? rec : x[i];
      x[h2] = up ? x[h2] : rec;
    }
  }

  // ---- second solve V = L^{-1} W^T ----
#pragma unroll
  for (int k = 0; k < 31; ++k) {
    float xk = x[k];
#pragma unroll
    for (int g = 0; g < 8; ++g) {
      if (4 * g + 3 <= k) continue;
      float4 L4 = *(const float4*)(Lh + k * 32 + 4 * g);
#pragma unroll
      for (int e = 0; e < 4; ++e) {
        int i = 4 * g + e;
        if (i > k) x[i] = fmaf(-f4c(L4, e), xk, x[i]);
      }
    }
  }

  // ---- A = D^{-1/2} V D^{-1/2} (dsv broadcast via LDS float4) ----
  vh[c] = dsv;
#pragma unroll
  for (int g = 0; g < 8; ++g) {
    float4 D4 = *(const float4*)(vh + 4 * g);
#pragma unroll
    for (int e = 0; e < 4; ++e) x[4 * g + e] *= f4c(D4, e) * dsv;
  }

  // ---- Householder tridiagonalization; d/e2 extracted in-loop ----
  float d[32], e2[31];
  float e2max = 0.0f, dminv = 1e30f, dmaxv = -1e30f;
#pragma unroll
  for (int k = 0; k < 30; ++k) {
    float colv = x[k];
    float dkk  = __shfl(x[k], k, 32);          // A[k][k], final at step k
    d[k] = dkk; dminv = fminf(dminv, dkk); dmaxv = fmaxf(dmaxv, dkk);
    float sq    = (c > k) ? colv * colv : 0.0f;
    float sigma = red32(sq);                   // ||A[k+1:,k]||^2
    float akk1  = __shfl(x[k], k + 1, 32);
    e2[k] = sigma; e2max = fmaxf(e2max, sigma);
    float nrm   = fsqrt_(sigma);
    float alpha = (akk1 >= 0.0f) ? -nrm : nrm;
    float denom = fmaf(-alpha, akk1, sigma);   // vTv/2
    float tau   = frcp(fmaxf(denom, 1e-35f));  // sigma==0 -> v==0 no-op
    float v     = (c == k + 1) ? (akk1 - alpha) : ((c > k + 1) ? colv : 0.0f);
    vh[c] = v;                                 // broadcast v via LDS
    float acc = 0.0f;
#pragma unroll
    for (int g = 0; g < 8; ++g) {              // acc_c = sum_j A[j][c] v_j
      if (4 * g + 3 <= k) continue;
      float4 V4 = *(const float4*)(vh + 4 * g);
#pragma unroll
      for (int e = 0; e < 4; ++e) {
        int j = 4 * g + e;
        if (j > k) acc = fmaf(x[j], f4c(V4, e), acc);
      }
    }
    float p = tau * acc;
    float K = 0.5f * tau * red32(v * p);
    float q = fmaf(-K, v, p);
    qh[c] = q;                                 // broadcast q via LDS
#pragma unroll
    for (int g = 0; g < 8; ++g) {              // A -= v q^T + q v^T
      if (4 * g + 3 <= k) continue;
      float4 V4 = *(const float4*)(vh + 4 * g);
      float4 Q4 = *(const float4*)(qh + 4 * g);
#pragma unroll
      for (int e = 0; e < 4; ++e) {
        int j = 4 * g + e;
        if (j > k) x[j] = fmaf(-v, f4c(Q4, e), fmaf(-q, f4c(V4, e), x[j]));
      }
    }
  }
  {
    float d30 = __shfl(x[30], 30, 32);
    float d31 = __shfl(x[31], 31, 32);
    float el  = __shfl(x[30], 31, 32);         // trailing subdiagonal
    d[30] = d30; d[31] = d31;
    e2[30] = el * el; e2max = fmaxf(e2max, e2[30]);
    dminv = fminf(dminv, fminf(d30, d31));
    dmaxv = fmaxf(dmaxv, fmaxf(d30, d31));
  }
  // x[] dead from here

  // ---- Gershgorin bounds ----
  float er = 2.0f * fsqrt_(e2max);
  float lo = fmaxf(dminv - er, 1e-3f);
  float hi = dmaxv + er;

  // ---- bisection with Sturm counts: lane c -> eigenvalue #c (pure VALU) ----
  for (int it = 0; it < 18; ++it) {
    float mid = 0.5f * (lo + hi);
    float qq  = d[0] - mid;
    qq = (fabsf(qq) < 1e-30f) ? -1e-30f : qq;
    int cnt = (qq < 0.0f) ? 1 : 0;
#pragma unroll
    for (int i = 1; i < 32; ++i) {
      qq = (d[i] - mid) - e2[i - 1] * frcp(qq);
      qq = (fabsf(qq) < 1e-30f) ? -1e-30f : qq;
      cnt += (qq < 0.0f) ? 1 : 0;
    }
    bool le = (cnt <= c);
    lo = le ? mid : lo;
    hi = le ? hi : mid;
  }

  float lam = 0.5f * (lo + hi);
  float lg  = __logf(lam);
  float s   = red32(lg * lg);
  float db  = fsqrt_(s);                       // d(x_b, y_b)

  if (c == 0) psum[hw] = db;
  __syncthreads();
  if (tid == 0) {
    float t = 0.0f;
#pragma unroll
    for (int i = 0; i < MPB; ++i) t += psum[i];
    partial[blockIdx.x] = t;
  }
}

__global__ __launch_bounds__(256) void riem_finish(const float* __restrict__ partial,
                                                   float* __restrict__ out) {
  float acc = 0.0f;
  for (int i = threadIdx.x; i < NBLK; i += 256) acc += partial[i];
  acc += __shfl_xor(acc, 1);
  acc += __shfl_xor(acc, 2);
  acc += __shfl_xor(acc, 4);
  acc += __shfl_xor(acc, 8);
  acc += __shfl_xor(acc, 16);
  acc += __shfl_xor(acc, 32);
  __shared__ float ps[4];
  if ((threadIdx.x & 63) == 0) ps[threadIdx.x >> 6] = acc;
  __syncthreads();
  if (threadIdx.x == 0)
    out[0] = (ps[0] + ps[1] + ps[2] + ps[3]) * (1.0f / (float)NMAT);
}

extern "C" void kernel_launch(void* const* d_in, const int* in_sizes, int n_in,
                              void* d_out, int out_size, void* d_ws, size_t ws_size,
                              hipStream_t stream) {
  const float* x = (const float*)d_in[0];
  const float* y = (const float*)d_in[1];
  float* out  = (float*)d_out;
  float* part = (float*)d_ws;   // NBLK floats = 25 KB
  riem_batch<<<NBLK, 256, 0, stream>>>(x, y, part);
  riem_finish<<<1, 256, 0, stream>>>(part, out);
}